// Round 1
// baseline (1059.534 us; speedup 1.0000x reference)
//
#include <hip/hip_runtime.h>
#include <math.h>

#define D_MODEL 1024
#define NUM_HEADS 16
#define D_K 64
#define B_SZ 2
#define T_SZ 2048
#define M_ROWS (B_SZ * T_SZ) // 4096

// ---------------------------------------------------------------------------
// GEMM (NT): Y[m][n] = sum_k X[m][k] * W[n][k]
// 64x64 tile, BK=16, 256 threads, 4x4 micro-tile.
// LDS tiles transposed [BK][BM] with stride 68 floats (=272B, 16B aligned,
// conflict-free / 2-way reads).
// ---------------------------------------------------------------------------
__global__ __launch_bounds__(256) void gemm_nt(
    const float* __restrict__ X, const float* __restrict__ W,
    float* __restrict__ Y, int Kdim, int Ndim)
{
    __shared__ float Xs[16][68];
    __shared__ float Ws[16][68];
    const int tx = threadIdx.x, ty = threadIdx.y;
    const int tid = ty * 16 + tx;
    const int lr = tid >> 2;          // 0..63 (tile row)
    const int lc = (tid & 3) << 2;    // 0,4,8,12 (k offset)
    const int m0 = blockIdx.y * 64, n0 = blockIdx.x * 64;

    float acc[4][4] = {};
    for (int k0 = 0; k0 < Kdim; k0 += 16) {
        float4 xv = *(const float4*)(X + (size_t)(m0 + lr) * Kdim + k0 + lc);
        float4 wv = *(const float4*)(W + (size_t)(n0 + lr) * Kdim + k0 + lc);
        Xs[lc + 0][lr] = xv.x; Xs[lc + 1][lr] = xv.y;
        Xs[lc + 2][lr] = xv.z; Xs[lc + 3][lr] = xv.w;
        Ws[lc + 0][lr] = wv.x; Ws[lc + 1][lr] = wv.y;
        Ws[lc + 2][lr] = wv.z; Ws[lc + 3][lr] = wv.w;
        __syncthreads();
#pragma unroll
        for (int k = 0; k < 16; ++k) {
            float a[4], b[4];
#pragma unroll
            for (int i = 0; i < 4; i++) a[i] = Xs[k][ty * 4 + i];
#pragma unroll
            for (int j = 0; j < 4; j++) b[j] = Ws[k][tx * 4 + j];
#pragma unroll
            for (int i = 0; i < 4; i++)
#pragma unroll
                for (int j = 0; j < 4; j++)
                    acc[i][j] = fmaf(a[i], b[j], acc[i][j]);
        }
        __syncthreads();
    }
#pragma unroll
    for (int i = 0; i < 4; i++) {
        float4 o = make_float4(acc[i][0], acc[i][1], acc[i][2], acc[i][3]);
        *(float4*)(Y + (size_t)(m0 + ty * 4 + i) * Ndim + n0 + tx * 4) = o;
    }
}

// ---------------------------------------------------------------------------
// RoPE applied in-place to Q and K. One thread per rotation pair.
// Layout: [b][t][h*64 + d]. Pair (i, i+32) within each head, i in [0,32).
// ---------------------------------------------------------------------------
__global__ __launch_bounds__(256) void rope_qk(float* __restrict__ Q,
                                               float* __restrict__ K)
{
    const int idx = blockIdx.x * 256 + threadIdx.x; // < B*T*H*32 = 2^21
    const int i = idx & 31;
    const int h = (idx >> 5) & (NUM_HEADS - 1);
    const int t = (idx >> 9) & (T_SZ - 1);
    const int b = idx >> 20;

    // inv_freq = 10000^(-i/32) computed in double, rounded to fp32 (matches
    // the fp32 reference table to ~1 ulp); freq = fp32(t) * fp32(invf) as ref.
    const float invf = (float)pow(10000.0, -(double)i / 32.0);
    const float fr = (float)t * invf;
    float s, c;
    sincosf(fr, &s, &c);

    const size_t base = ((size_t)(b * T_SZ + t)) * D_MODEL + h * D_K + i;
    float q1 = Q[base], q2 = Q[base + 32];
    Q[base] = q1 * c - q2 * s;
    Q[base + 32] = q1 * s + q2 * c;
    float k1 = K[base], k2 = K[base + 32];
    K[base] = k1 * c - k2 * s;
    K[base + 32] = k1 * s + k2 * c;
}

// ---------------------------------------------------------------------------
// Flash-style attention. One block = 64 query rows of one (b,h).
// Q,K transposed in LDS [d][row]; V direct [row][d]; S [qrow][krow].
// Online softmax: 4 lanes per row, shfl_xor reductions.
// ---------------------------------------------------------------------------
__global__ __launch_bounds__(256) void attn(
    const float* __restrict__ Q, const float* __restrict__ K,
    const float* __restrict__ V, float* __restrict__ O)
{
    __shared__ float Qs[64][68]; // [d][qrow]
    __shared__ float Ks[64][68]; // [d][krow]
    __shared__ float Vs[64][68]; // [krow][d]
    __shared__ float Ss[64][68]; // [qrow][krow] -> then P
    __shared__ float mrun[64], lrun[64], rowscale[64];

    const int tx = threadIdx.x, ty = threadIdx.y;
    const int tid = ty * 16 + tx;
    const int bh = blockIdx.y;
    const int b = bh >> 4, h = bh & (NUM_HEADS - 1);
    const int q0 = blockIdx.x * 64;
    const int lr = tid >> 2;         // 0..63
    const int c0 = (tid & 3) * 16;   // 0,16,32,48

    const size_t headoff = (size_t)h * D_K;

    // Load Q tile transposed
    {
        const float* src = Q + ((size_t)(b * T_SZ + q0 + lr)) * D_MODEL + headoff + c0;
#pragma unroll
        for (int u = 0; u < 4; u++) {
            float4 v = *(const float4*)(src + 4 * u);
            Qs[c0 + 4 * u + 0][lr] = v.x; Qs[c0 + 4 * u + 1][lr] = v.y;
            Qs[c0 + 4 * u + 2][lr] = v.z; Qs[c0 + 4 * u + 3][lr] = v.w;
        }
    }
    if (tid < 64) { mrun[tid] = -INFINITY; lrun[tid] = 0.f; }
    float acc[4][4] = {};
    __syncthreads();

    for (int kt = 0; kt < T_SZ; kt += 64) {
        // Load K (transposed) and V (direct) tiles
        {
            const float* ksrc = K + ((size_t)(b * T_SZ + kt + lr)) * D_MODEL + headoff + c0;
            const float* vsrc = V + ((size_t)(b * T_SZ + kt + lr)) * D_MODEL + headoff + c0;
#pragma unroll
            for (int u = 0; u < 4; u++) {
                float4 kv = *(const float4*)(ksrc + 4 * u);
                Ks[c0 + 4 * u + 0][lr] = kv.x; Ks[c0 + 4 * u + 1][lr] = kv.y;
                Ks[c0 + 4 * u + 2][lr] = kv.z; Ks[c0 + 4 * u + 3][lr] = kv.w;
                float4 vv = *(const float4*)(vsrc + 4 * u);
                *(float4*)&Vs[lr][c0 + 4 * u] = vv;
            }
        }
        __syncthreads();

        // S = (Q K^T) * 1/sqrt(dk)
        float sacc[4][4] = {};
#pragma unroll
        for (int d = 0; d < 64; ++d) {
            float a[4], bb[4];
#pragma unroll
            for (int i = 0; i < 4; i++) a[i] = Qs[d][ty * 4 + i];
#pragma unroll
            for (int j = 0; j < 4; j++) bb[j] = Ks[d][tx * 4 + j];
#pragma unroll
            for (int i = 0; i < 4; i++)
#pragma unroll
                for (int j = 0; j < 4; j++)
                    sacc[i][j] = fmaf(a[i], bb[j], sacc[i][j]);
        }
#pragma unroll
        for (int i = 0; i < 4; i++) {
            float4 o = make_float4(sacc[i][0] * 0.125f, sacc[i][1] * 0.125f,
                                   sacc[i][2] * 0.125f, sacc[i][3] * 0.125f);
            *(float4*)&Ss[ty * 4 + i][tx * 4] = o;
        }
        __syncthreads();

        // Online softmax update: 4 lanes per row
        {
            const int row = tid >> 2, qq = tid & 3;
            float vals[16];
            float pm = -INFINITY;
#pragma unroll
            for (int u = 0; u < 16; u++) {
                vals[u] = Ss[row][qq * 16 + u];
                pm = fmaxf(pm, vals[u]);
            }
            pm = fmaxf(pm, __shfl_xor(pm, 1));
            pm = fmaxf(pm, __shfl_xor(pm, 2));
            const float mo = mrun[row];
            const float mn = fmaxf(mo, pm);
            const float sc = __expf(mo - mn); // exp(-inf)=0 on first tile
            float ps = 0.f;
#pragma unroll
            for (int u = 0; u < 16; u++) {
                float p = __expf(vals[u] - mn);
                ps += p;
                Ss[row][qq * 16 + u] = p;
            }
            ps += __shfl_xor(ps, 1);
            ps += __shfl_xor(ps, 2);
            if (qq == 0) {
                mrun[row] = mn;
                lrun[row] = lrun[row] * sc + ps;
                rowscale[row] = sc;
            }
        }
        __syncthreads();

        // Rescale accumulator, then O += P @ V
        float rs[4];
#pragma unroll
        for (int i = 0; i < 4; i++) rs[i] = rowscale[ty * 4 + i];
#pragma unroll
        for (int i = 0; i < 4; i++)
#pragma unroll
            for (int j = 0; j < 4; j++) acc[i][j] *= rs[i];
#pragma unroll
        for (int k = 0; k < 64; ++k) {
            float a[4], bb[4];
#pragma unroll
            for (int i = 0; i < 4; i++) a[i] = Ss[ty * 4 + i][k];
#pragma unroll
            for (int j = 0; j < 4; j++) bb[j] = Vs[k][tx * 4 + j];
#pragma unroll
            for (int i = 0; i < 4; i++)
#pragma unroll
                for (int j = 0; j < 4; j++)
                    acc[i][j] = fmaf(a[i], bb[j], acc[i][j]);
        }
        __syncthreads();
    }

    // Normalize and store O in [b][t][h*64+d] layout
#pragma unroll
    for (int i = 0; i < 4; i++) {
        const float inv = 1.f / lrun[ty * 4 + i];
        float4 o = make_float4(acc[i][0] * inv, acc[i][1] * inv,
                               acc[i][2] * inv, acc[i][3] * inv);
        *(float4*)(O + ((size_t)(b * T_SZ + q0 + ty * 4 + i)) * D_MODEL +
                   headoff + tx * 4) = o;
    }
}

// ---------------------------------------------------------------------------
extern "C" void kernel_launch(void* const* d_in, const int* in_sizes, int n_in,
                              void* d_out, int out_size, void* d_ws, size_t ws_size,
                              hipStream_t stream)
{
    const float* x  = (const float*)d_in[0];
    const float* wq = (const float*)d_in[1];
    const float* wk = (const float*)d_in[2];
    const float* wv = (const float*)d_in[3];
    const float* wo = (const float*)d_in[4];
    float* out = (float*)d_out;

    float* Q = (float*)d_ws;
    float* K = Q + (size_t)M_ROWS * D_MODEL;
    float* V = K + (size_t)M_ROWS * D_MODEL;
    float* O = V + (size_t)M_ROWS * D_MODEL;

    dim3 blk(16, 16);
    dim3 ggrid(D_MODEL / 64, M_ROWS / 64);

    gemm_nt<<<ggrid, blk, 0, stream>>>(x, wq, Q, D_MODEL, D_MODEL);
    gemm_nt<<<ggrid, blk, 0, stream>>>(x, wk, K, D_MODEL, D_MODEL);
    gemm_nt<<<ggrid, blk, 0, stream>>>(x, wv, V, D_MODEL, D_MODEL);

    const int npairs = B_SZ * T_SZ * NUM_HEADS * 32;
    rope_qk<<<dim3(npairs / 256), dim3(256), 0, stream>>>(Q, K);

    attn<<<dim3(T_SZ / 64, B_SZ * NUM_HEADS), blk, 0, stream>>>(Q, K, V, O);

    gemm_nt<<<ggrid, blk, 0, stream>>>(O, wo, out, D_MODEL, D_MODEL);
}

// Round 2
// 293.860 us; speedup vs baseline: 3.6056x; 3.6056x over previous
//
#include <hip/hip_runtime.h>
#include <math.h>

typedef __attribute__((ext_vector_type(8))) short short8;
typedef __attribute__((ext_vector_type(4))) float f32x4;

#define D_MODEL 1024
#define NUM_HEADS 16
#define D_K 64
#define B_SZ 2
#define T_SZ 2048
#define M_ROWS (B_SZ * T_SZ) // 4096
#define LSTR 72              // attn LDS row stride (bf16 elems): 144B, 16B-aligned, 36 dwords

__device__ __forceinline__ unsigned short f2bf(float f) {
    union { float f; unsigned int u; } v; v.f = f;
    unsigned int r = v.u + 0x7FFF + ((v.u >> 16) & 1); // RNE
    return (unsigned short)(r >> 16);
}
__device__ __forceinline__ float bf2f(unsigned short s) {
    union { unsigned int u; float f; } v; v.u = ((unsigned int)s) << 16;
    return v.f;
}
__device__ __forceinline__ void gload_lds16(const void* g, void* l) {
    __builtin_amdgcn_global_load_lds(
        (const __attribute__((address_space(1))) unsigned int*)g,
        (__attribute__((address_space(3))) unsigned int*)l, 16, 0, 0);
}

// ---------------------------------------------------------------------------
// fp32 -> bf16 conversion, 8 elems/thread
// ---------------------------------------------------------------------------
__global__ __launch_bounds__(256) void cvt_bf16(const float* __restrict__ in,
                                                unsigned short* __restrict__ out,
                                                int n8)
{
    int i = blockIdx.x * 256 + threadIdx.x;
    if (i >= n8) return;
    const float4* p = (const float4*)in + 2 * (size_t)i;
    float4 a = p[0], b = p[1];
    short8 o;
    o[0] = f2bf(a.x); o[1] = f2bf(a.y); o[2] = f2bf(a.z); o[3] = f2bf(a.w);
    o[4] = f2bf(b.x); o[5] = f2bf(b.y); o[6] = f2bf(b.z); o[7] = f2bf(b.w);
    *((short8*)out + i) = o;
}

// ---------------------------------------------------------------------------
// bf16 MFMA GEMM (NT): Y[m][n] = sum_k X[m][k]*W[n][k].  m97 structure:
// 128x128 tile, BK=32, 4 waves (2x2), global_load_lds(16B), linear LDS.
// z selects {wq,wk,wv} -> {Q,K,V}.
// ---------------------------------------------------------------------------
__global__ __launch_bounds__(256) void gemm_qkv(
    const unsigned short* __restrict__ Xb,
    const unsigned short* __restrict__ Wq,
    const unsigned short* __restrict__ Wk,
    const unsigned short* __restrict__ Wv,
    unsigned short* __restrict__ Qb,
    unsigned short* __restrict__ Kb,
    unsigned short* __restrict__ Vb)
{
    const int z = blockIdx.z;
    const unsigned short* W = (z == 0) ? Wq : (z == 1) ? Wk : Wv;
    unsigned short* Y = (z == 0) ? Qb : (z == 1) ? Kb : Vb;

    __shared__ unsigned short Als[128 * 32];
    __shared__ unsigned short Bls[128 * 32];

    const int tid = threadIdx.x;
    const int lane = tid & 63, wid = tid >> 6;
    const int g = lane >> 4, c16 = lane & 15;
    const int wr = wid >> 1, wc = wid & 1;
    const int m0 = blockIdx.y * 128, n0 = blockIdx.x * 128;

    const int sr = tid >> 2, sc = (tid & 3) * 8;
    const unsigned short* xg = Xb + (size_t)(m0 + sr) * D_MODEL + sc;
    const unsigned short* wg = W + (size_t)(n0 + sr) * D_MODEL + sc;
    unsigned short* adst = Als + wid * 512; // wave-uniform LDS dst (lane*16B implicit)
    unsigned short* bdst = Bls + wid * 512;

    f32x4 acc[4][4] = {};

    for (int k0 = 0; k0 < D_MODEL; k0 += 32) {
        __syncthreads();
        gload_lds16(xg + k0, adst);
        gload_lds16(xg + k0 + (size_t)64 * D_MODEL, adst + 2048);
        gload_lds16(wg + k0, bdst);
        gload_lds16(wg + k0 + (size_t)64 * D_MODEL, bdst + 2048);
        __syncthreads();
        short8 af[4], bf[4];
#pragma unroll
        for (int mf = 0; mf < 4; mf++)
            af[mf] = *(const short8*)&Als[(wr * 64 + mf * 16 + c16) * 32 + g * 8];
#pragma unroll
        for (int nf = 0; nf < 4; nf++)
            bf[nf] = *(const short8*)&Bls[(wc * 64 + nf * 16 + c16) * 32 + g * 8];
#pragma unroll
        for (int mf = 0; mf < 4; mf++)
#pragma unroll
            for (int nf = 0; nf < 4; nf++)
                acc[mf][nf] = __builtin_amdgcn_mfma_f32_16x16x32_bf16(
                    af[mf], bf[nf], acc[mf][nf], 0, 0, 0);
    }

#pragma unroll
    for (int mf = 0; mf < 4; mf++)
#pragma unroll
        for (int nf = 0; nf < 4; nf++)
#pragma unroll
            for (int j = 0; j < 4; j++) {
                int row = m0 + wr * 64 + mf * 16 + g * 4 + j;
                int col = n0 + wc * 64 + nf * 16 + c16;
                Y[(size_t)row * D_MODEL + col] = f2bf(acc[mf][nf][j]);
            }
}

// Same structure, bf16 in -> fp32 out (final projection)
__global__ __launch_bounds__(256) void gemm_out(
    const unsigned short* __restrict__ Xb,
    const unsigned short* __restrict__ W,
    float* __restrict__ Y)
{
    __shared__ unsigned short Als[128 * 32];
    __shared__ unsigned short Bls[128 * 32];

    const int tid = threadIdx.x;
    const int lane = tid & 63, wid = tid >> 6;
    const int g = lane >> 4, c16 = lane & 15;
    const int wr = wid >> 1, wc = wid & 1;
    const int m0 = blockIdx.y * 128, n0 = blockIdx.x * 128;

    const int sr = tid >> 2, sc = (tid & 3) * 8;
    const unsigned short* xg = Xb + (size_t)(m0 + sr) * D_MODEL + sc;
    const unsigned short* wg = W + (size_t)(n0 + sr) * D_MODEL + sc;
    unsigned short* adst = Als + wid * 512;
    unsigned short* bdst = Bls + wid * 512;

    f32x4 acc[4][4] = {};

    for (int k0 = 0; k0 < D_MODEL; k0 += 32) {
        __syncthreads();
        gload_lds16(xg + k0, adst);
        gload_lds16(xg + k0 + (size_t)64 * D_MODEL, adst + 2048);
        gload_lds16(wg + k0, bdst);
        gload_lds16(wg + k0 + (size_t)64 * D_MODEL, bdst + 2048);
        __syncthreads();
        short8 af[4], bf[4];
#pragma unroll
        for (int mf = 0; mf < 4; mf++)
            af[mf] = *(const short8*)&Als[(wr * 64 + mf * 16 + c16) * 32 + g * 8];
#pragma unroll
        for (int nf = 0; nf < 4; nf++)
            bf[nf] = *(const short8*)&Bls[(wc * 64 + nf * 16 + c16) * 32 + g * 8];
#pragma unroll
        for (int mf = 0; mf < 4; mf++)
#pragma unroll
            for (int nf = 0; nf < 4; nf++)
                acc[mf][nf] = __builtin_amdgcn_mfma_f32_16x16x32_bf16(
                    af[mf], bf[nf], acc[mf][nf], 0, 0, 0);
    }

#pragma unroll
    for (int mf = 0; mf < 4; mf++)
#pragma unroll
        for (int nf = 0; nf < 4; nf++)
#pragma unroll
            for (int j = 0; j < 4; j++) {
                int row = m0 + wr * 64 + mf * 16 + g * 4 + j;
                int col = n0 + wc * 64 + nf * 16 + c16;
                Y[(size_t)row * D_MODEL + col] = acc[mf][nf][j];
            }
}

// ---------------------------------------------------------------------------
// RoPE in-place on bf16 Q,K; folds 1/sqrt(dk)=0.125 into Q (exact pow2).
// ---------------------------------------------------------------------------
__global__ __launch_bounds__(256) void rope_bf16(unsigned short* __restrict__ Q,
                                                 unsigned short* __restrict__ K)
{
    const int idx = blockIdx.x * 256 + threadIdx.x;
    const int i = idx & 31;
    const int h = (idx >> 5) & (NUM_HEADS - 1);
    const int t = (idx >> 9) & (T_SZ - 1);
    const int b = idx >> 20;
    const float invf = (float)pow(10000.0, -(double)i / 32.0);
    const float fr = (float)t * invf;
    float s, c;
    sincosf(fr, &s, &c);
    const size_t base = (size_t)(b * T_SZ + t) * D_MODEL + h * D_K + i;
    float q1 = bf2f(Q[base]), q2 = bf2f(Q[base + 32]);
    Q[base]      = f2bf((q1 * c - q2 * s) * 0.125f);
    Q[base + 32] = f2bf((q1 * s + q2 * c) * 0.125f);
    float k1 = bf2f(K[base]), k2 = bf2f(K[base + 32]);
    K[base]      = f2bf(k1 * c - k2 * s);
    K[base + 32] = f2bf(k1 * s + k2 * c);
}

// ---------------------------------------------------------------------------
// Flash attention, MFMA 16x16x32. Block = 64 q-rows of one (b,h), 4 waves x
// 16 rows. Q in regs; K and V^T staged in LDS (stride-72 rows + add-rotate
// column-block swizzle, keeps NT-pattern ds_read_b128 near conflict floor);
// P goes D-layout -> A-layout via per-wave LDS buffer (same-wave dep only).
// ---------------------------------------------------------------------------
__global__ __launch_bounds__(256) void attn_mfma(
    const unsigned short* __restrict__ Qb,
    const unsigned short* __restrict__ Kb,
    const unsigned short* __restrict__ Vb,
    unsigned short* __restrict__ Ob)
{
    __shared__ unsigned short Ks[64 * LSTR];     // [kv][d], col-blocks rotated by kv>>3
    __shared__ unsigned short Vt[64 * LSTR];     // [d][kv], col-blocks rotated by d>>3
    __shared__ unsigned short Ps[4][16 * LSTR];  // per-wave P [q][kv], rotated by q

    const int tid = threadIdx.x;
    const int lane = tid & 63, wid = tid >> 6;
    const int g = lane >> 4, c16 = lane & 15;
    const int bh = blockIdx.y, b = bh >> 4, h = bh & (NUM_HEADS - 1);
    const int q0 = blockIdx.x * 64;

    // Q fragments (A-layout): row = c16, k = g*8 (+32)
    const unsigned short* qsrc =
        Qb + (size_t)(b * T_SZ + q0 + wid * 16 + c16) * D_MODEL + h * D_K + g * 8;
    short8 qf0 = *(const short8*)qsrc;
    short8 qf1 = *(const short8*)(qsrc + 32);

    f32x4 acc[4] = {};
    float mrow[4] = {-INFINITY, -INFINITY, -INFINITY, -INFINITY};
    float lrow[4] = {};

    const int kr = tid >> 2, kcb = tid & 3;  // K staging: row, col-block pair
    const int vr = tid >> 3, vc = tid & 7;   // V staging: kv row (+32), d-block
    const unsigned short* kbase = Kb + (size_t)b * T_SZ * D_MODEL + h * D_K;
    const unsigned short* vbase = Vb + (size_t)b * T_SZ * D_MODEL + h * D_K;

    for (int kt = 0; kt < T_SZ; kt += 64) {
        __syncthreads();
        { // stage K tile [64 kv][64 d]
            const unsigned short* s = kbase + (size_t)(kt + kr) * D_MODEL;
            short8 a = *(const short8*)(s + kcb * 8);
            short8 bq = *(const short8*)(s + (kcb + 4) * 8);
            *(short8*)&Ks[kr * LSTR + ((kcb + (kr >> 3)) & 7) * 8] = a;
            *(short8*)&Ks[kr * LSTR + ((kcb + 4 + (kr >> 3)) & 7) * 8] = bq;
        }
        { // stage V transposed: Vt[d][kv]
            const unsigned short* s = vbase + (size_t)(kt + vr) * D_MODEL + vc * 8;
            short8 v0 = *(const short8*)s;
            short8 v1 = *(const short8*)(s + (size_t)32 * D_MODEL);
#pragma unroll
            for (int u = 0; u < 8; u++) {
                int d = vc * 8 + u;
                Vt[d * LSTR + ((((vr >> 3) + vc) & 7) * 8) + (vr & 7)] =
                    (unsigned short)v0[u];
                Vt[d * LSTR + (((((vr + 32) >> 3) + vc) & 7) * 8) + (vr & 7)] =
                    (unsigned short)v1[u];
            }
        }
        __syncthreads();

        // S = Q K^T (scale pre-folded into Q)
        f32x4 sacc[4] = {};
#pragma unroll
        for (int ks = 0; ks < 2; ks++)
#pragma unroll
            for (int nf = 0; nf < 4; nf++) {
                int row = nf * 16 + c16;
                short8 kf = *(const short8*)
                    &Ks[row * LSTR + (((ks * 4 + g) + (row >> 3)) & 7) * 8];
                sacc[nf] = __builtin_amdgcn_mfma_f32_16x16x32_bf16(
                    ks == 0 ? qf0 : qf1, kf, sacc[nf], 0, 0, 0);
            }

        // online softmax (rows (g*4+j); 16-lane shfl reductions)
        float scale[4];
#pragma unroll
        for (int j = 0; j < 4; j++) {
            float pm = fmaxf(fmaxf(sacc[0][j], sacc[1][j]),
                             fmaxf(sacc[2][j], sacc[3][j]));
            pm = fmaxf(pm, __shfl_xor(pm, 1));
            pm = fmaxf(pm, __shfl_xor(pm, 2));
            pm = fmaxf(pm, __shfl_xor(pm, 4));
            pm = fmaxf(pm, __shfl_xor(pm, 8));
            float mn = fmaxf(mrow[j], pm);
            scale[j] = __expf(mrow[j] - mn); // first tile: exp(-inf)=0
            mrow[j] = mn;
            float ps = 0.f;
#pragma unroll
            for (int nf = 0; nf < 4; nf++) {
                float p = __expf(sacc[nf][j] - mn);
                sacc[nf][j] = p;
                ps += p;
            }
            ps += __shfl_xor(ps, 1);
            ps += __shfl_xor(ps, 2);
            ps += __shfl_xor(ps, 4);
            ps += __shfl_xor(ps, 8);
            lrow[j] = lrow[j] * scale[j] + ps;
        }

        // P: D-layout -> per-wave LDS (A-layout source). Same-wave dependency,
        // no barrier needed (compiler inserts lgkmcnt wait).
#pragma unroll
        for (int nf = 0; nf < 4; nf++)
#pragma unroll
            for (int j = 0; j < 4; j++) {
                int q = g * 4 + j, kv = nf * 16 + c16;
                Ps[wid][q * LSTR + ((((kv >> 3) + q) & 7) * 8) + (kv & 7)] =
                    f2bf(sacc[nf][j]);
            }
        short8 pf0 = *(const short8*)&Ps[wid][c16 * LSTR + ((g + c16) & 7) * 8];
        short8 pf1 = *(const short8*)&Ps[wid][c16 * LSTR + (((4 + g) + c16) & 7) * 8];

        // rescale O accumulator
#pragma unroll
        for (int nf = 0; nf < 4; nf++)
#pragma unroll
            for (int j = 0; j < 4; j++) acc[nf][j] *= scale[j];

        // O += P V
#pragma unroll
        for (int ks = 0; ks < 2; ks++)
#pragma unroll
            for (int nf = 0; nf < 4; nf++) {
                int row = nf * 16 + c16;
                short8 vf = *(const short8*)
                    &Vt[row * LSTR + (((ks * 4 + g) + (row >> 3)) & 7) * 8];
                acc[nf] = __builtin_amdgcn_mfma_f32_16x16x32_bf16(
                    ks == 0 ? pf0 : pf1, vf, acc[nf], 0, 0, 0);
            }
    }

    // normalize, store bf16 O
#pragma unroll
    for (int nf = 0; nf < 4; nf++)
#pragma unroll
        for (int j = 0; j < 4; j++) {
            int q = g * 4 + j;
            float v = acc[nf][j] / lrow[j];
            Ob[(size_t)(b * T_SZ + q0 + wid * 16 + q) * D_MODEL + h * D_K +
               nf * 16 + c16] = f2bf(v);
        }
}

// ---------------------------------------------------------------------------
extern "C" void kernel_launch(void* const* d_in, const int* in_sizes, int n_in,
                              void* d_out, int out_size, void* d_ws, size_t ws_size,
                              hipStream_t stream)
{
    const float* x  = (const float*)d_in[0];
    const float* wq = (const float*)d_in[1];
    const float* wk = (const float*)d_in[2];
    const float* wv = (const float*)d_in[3];
    const float* wo = (const float*)d_in[4];
    float* out = (float*)d_out;

    const size_t NX = (size_t)M_ROWS * D_MODEL; // 4M
    const size_t NW = (size_t)D_MODEL * D_MODEL; // 1M
    unsigned short* xb  = (unsigned short*)d_ws;
    unsigned short* wqb = xb + NX;
    unsigned short* wkb = wqb + NW;
    unsigned short* wvb = wkb + NW;
    unsigned short* wob = wvb + NW;
    unsigned short* Qb  = wob + NW;
    unsigned short* Kb  = Qb + NX;
    unsigned short* Vb  = Kb + NX;
    unsigned short* Ob  = Vb + NX;   // total 24M ushorts = 48 MB

    cvt_bf16<<<dim3((int)(NX / 8 / 256)), dim3(256), 0, stream>>>(x, xb, (int)(NX / 8));
    cvt_bf16<<<dim3((int)(NW / 8 / 256)), dim3(256), 0, stream>>>(wq, wqb, (int)(NW / 8));
    cvt_bf16<<<dim3((int)(NW / 8 / 256)), dim3(256), 0, stream>>>(wk, wkb, (int)(NW / 8));
    cvt_bf16<<<dim3((int)(NW / 8 / 256)), dim3(256), 0, stream>>>(wv, wvb, (int)(NW / 8));
    cvt_bf16<<<dim3((int)(NW / 8 / 256)), dim3(256), 0, stream>>>(wo, wob, (int)(NW / 8));

    gemm_qkv<<<dim3(D_MODEL / 128, M_ROWS / 128, 3), dim3(256), 0, stream>>>(
        xb, wqb, wkb, wvb, Qb, Kb, Vb);

    const int npairs = B_SZ * T_SZ * NUM_HEADS * 32;
    rope_bf16<<<dim3(npairs / 256), dim3(256), 0, stream>>>(Qb, Kb);

    attn_mfma<<<dim3(T_SZ / 64, B_SZ * NUM_HEADS), dim3(256), 0, stream>>>(Qb, Kb, Vb, Ob);

    gemm_out<<<dim3(D_MODEL / 128, M_ROWS / 128), dim3(256), 0, stream>>>(Ob, wob, out);
}

// Round 3
// 241.990 us; speedup vs baseline: 4.3784x; 1.2144x over previous
//
#include <hip/hip_runtime.h>
#include <math.h>

typedef __attribute__((ext_vector_type(8))) short short8;
typedef __attribute__((ext_vector_type(4))) float f32x4;
typedef __attribute__((ext_vector_type(16))) float f32x16;

#define D_MODEL 1024
#define NUM_HEADS 16
#define D_K 64
#define B_SZ 2
#define T_SZ 2048
#define M_ROWS (B_SZ * T_SZ) // 4096
#define LSTR 72              // LDS row stride (bf16 elems): 144B
#define LOG2E 1.4426950408889634f

__device__ __forceinline__ unsigned short f2bf(float f) {
    union { float f; unsigned int u; } v; v.f = f;
    unsigned int r = v.u + 0x7FFF + ((v.u >> 16) & 1); // RNE
    return (unsigned short)(r >> 16);
}
__device__ __forceinline__ float bf2f(unsigned short s) {
    union { unsigned int u; float f; } v; v.u = ((unsigned int)s) << 16;
    return v.f;
}
__device__ __forceinline__ void gload_lds16(const void* g, void* l) {
    __builtin_amdgcn_global_load_lds(
        (const __attribute__((address_space(1))) unsigned int*)g,
        (__attribute__((address_space(3))) unsigned int*)l, 16, 0, 0);
}
__device__ __forceinline__ int cvtpk(float lo, float hi) {
    int r;
    asm("v_cvt_pk_bf16_f32 %0, %1, %2" : "=v"(r) : "v"(lo), "v"(hi));
    return r;
}

// ---------------------------------------------------------------------------
// fp32 -> bf16 conversion, 8 elems/thread
// ---------------------------------------------------------------------------
__global__ __launch_bounds__(256) void cvt_bf16(const float* __restrict__ in,
                                                unsigned short* __restrict__ out,
                                                int n8)
{
    int i = blockIdx.x * 256 + threadIdx.x;
    if (i >= n8) return;
    const float4* p = (const float4*)in + 2 * (size_t)i;
    float4 a = p[0], b = p[1];
    short8 o;
    o[0] = f2bf(a.x); o[1] = f2bf(a.y); o[2] = f2bf(a.z); o[3] = f2bf(a.w);
    o[4] = f2bf(b.x); o[5] = f2bf(b.y); o[6] = f2bf(b.z); o[7] = f2bf(b.w);
    *((short8*)out + i) = o;
}

// ---------------------------------------------------------------------------
// bf16 MFMA GEMM (NT), m97 structure: 128x128 tile, BK=32, 4 waves,
// global_load_lds(16B). z selects {wq,wk,wv}.
// ---------------------------------------------------------------------------
__global__ __launch_bounds__(256) void gemm_qkv(
    const unsigned short* __restrict__ Xb,
    const unsigned short* __restrict__ Wq,
    const unsigned short* __restrict__ Wk,
    const unsigned short* __restrict__ Wv,
    unsigned short* __restrict__ Qb,
    unsigned short* __restrict__ Kb,
    unsigned short* __restrict__ Vb)
{
    const int z = blockIdx.z;
    const unsigned short* W = (z == 0) ? Wq : (z == 1) ? Wk : Wv;
    unsigned short* Y = (z == 0) ? Qb : (z == 1) ? Kb : Vb;

    __shared__ unsigned short Als[128 * 32];
    __shared__ unsigned short Bls[128 * 32];

    const int tid = threadIdx.x;
    const int lane = tid & 63, wid = tid >> 6;
    const int g = lane >> 4, c16 = lane & 15;
    const int wr = wid >> 1, wc = wid & 1;
    const int m0 = blockIdx.y * 128, n0 = blockIdx.x * 128;

    const int sr = tid >> 2, sc = (tid & 3) * 8;
    const unsigned short* xg = Xb + (size_t)(m0 + sr) * D_MODEL + sc;
    const unsigned short* wg = W + (size_t)(n0 + sr) * D_MODEL + sc;
    unsigned short* adst = Als + wid * 512;
    unsigned short* bdst = Bls + wid * 512;

    f32x4 acc[4][4] = {};

    for (int k0 = 0; k0 < D_MODEL; k0 += 32) {
        __syncthreads();
        gload_lds16(xg + k0, adst);
        gload_lds16(xg + k0 + (size_t)64 * D_MODEL, adst + 2048);
        gload_lds16(wg + k0, bdst);
        gload_lds16(wg + k0 + (size_t)64 * D_MODEL, bdst + 2048);
        __syncthreads();
        short8 af[4], bf[4];
#pragma unroll
        for (int mf = 0; mf < 4; mf++)
            af[mf] = *(const short8*)&Als[(wr * 64 + mf * 16 + c16) * 32 + g * 8];
#pragma unroll
        for (int nf = 0; nf < 4; nf++)
            bf[nf] = *(const short8*)&Bls[(wc * 64 + nf * 16 + c16) * 32 + g * 8];
#pragma unroll
        for (int mf = 0; mf < 4; mf++)
#pragma unroll
            for (int nf = 0; nf < 4; nf++)
                acc[mf][nf] = __builtin_amdgcn_mfma_f32_16x16x32_bf16(
                    af[mf], bf[nf], acc[mf][nf], 0, 0, 0);
    }

#pragma unroll
    for (int mf = 0; mf < 4; mf++)
#pragma unroll
        for (int nf = 0; nf < 4; nf++)
#pragma unroll
            for (int j = 0; j < 4; j++) {
                int row = m0 + wr * 64 + mf * 16 + g * 4 + j;
                int col = n0 + wc * 64 + nf * 16 + c16;
                Y[(size_t)row * D_MODEL + col] = f2bf(acc[mf][nf][j]);
            }
}

// Same structure, bf16 in -> fp32 out (final projection)
__global__ __launch_bounds__(256) void gemm_out(
    const unsigned short* __restrict__ Xb,
    const unsigned short* __restrict__ W,
    float* __restrict__ Y)
{
    __shared__ unsigned short Als[128 * 32];
    __shared__ unsigned short Bls[128 * 32];

    const int tid = threadIdx.x;
    const int lane = tid & 63, wid = tid >> 6;
    const int g = lane >> 4, c16 = lane & 15;
    const int wr = wid >> 1, wc = wid & 1;
    const int m0 = blockIdx.y * 128, n0 = blockIdx.x * 128;

    const int sr = tid >> 2, sc = (tid & 3) * 8;
    const unsigned short* xg = Xb + (size_t)(m0 + sr) * D_MODEL + sc;
    const unsigned short* wg = W + (size_t)(n0 + sr) * D_MODEL + sc;
    unsigned short* adst = Als + wid * 512;
    unsigned short* bdst = Bls + wid * 512;

    f32x4 acc[4][4] = {};

    for (int k0 = 0; k0 < D_MODEL; k0 += 32) {
        __syncthreads();
        gload_lds16(xg + k0, adst);
        gload_lds16(xg + k0 + (size_t)64 * D_MODEL, adst + 2048);
        gload_lds16(wg + k0, bdst);
        gload_lds16(wg + k0 + (size_t)64 * D_MODEL, bdst + 2048);
        __syncthreads();
        short8 af[4], bf[4];
#pragma unroll
        for (int mf = 0; mf < 4; mf++)
            af[mf] = *(const short8*)&Als[(wr * 64 + mf * 16 + c16) * 32 + g * 8];
#pragma unroll
        for (int nf = 0; nf < 4; nf++)
            bf[nf] = *(const short8*)&Bls[(wc * 64 + nf * 16 + c16) * 32 + g * 8];
#pragma unroll
        for (int mf = 0; mf < 4; mf++)
#pragma unroll
            for (int nf = 0; nf < 4; nf++)
                acc[mf][nf] = __builtin_amdgcn_mfma_f32_16x16x32_bf16(
                    af[mf], bf[nf], acc[mf][nf], 0, 0, 0);
    }

#pragma unroll
    for (int mf = 0; mf < 4; mf++)
#pragma unroll
        for (int nf = 0; nf < 4; nf++)
#pragma unroll
            for (int j = 0; j < 4; j++) {
                int row = m0 + wr * 64 + mf * 16 + g * 4 + j;
                int col = n0 + wc * 64 + nf * 16 + c16;
                Y[(size_t)row * D_MODEL + col] = acc[mf][nf][j];
            }
}

// ---------------------------------------------------------------------------
// RoPE in-place on bf16 Q,K; folds 0.125*log2(e) into Q (exp2 softmax).
// ---------------------------------------------------------------------------
__global__ __launch_bounds__(256) void rope_bf16(unsigned short* __restrict__ Q,
                                                 unsigned short* __restrict__ K)
{
    const int idx = blockIdx.x * 256 + threadIdx.x;
    const int i = idx & 31;
    const int h = (idx >> 5) & (NUM_HEADS - 1);
    const int t = (idx >> 9) & (T_SZ - 1);
    const int b = idx >> 20;
    const float invf = (float)pow(10000.0, -(double)i / 32.0);
    const float fr = (float)t * invf;
    float s, c;
    sincosf(fr, &s, &c);
    const float qs = 0.125f * LOG2E;
    const size_t base = (size_t)(b * T_SZ + t) * D_MODEL + h * D_K + i;
    float q1 = bf2f(Q[base]), q2 = bf2f(Q[base + 32]);
    Q[base]      = f2bf((q1 * c - q2 * s) * qs);
    Q[base + 32] = f2bf((q1 * s + q2 * c) * qs);
    float k1 = bf2f(K[base]), k2 = bf2f(K[base + 32]);
    K[base]      = f2bf(k1 * c - k2 * s);
    K[base + 32] = f2bf(k1 * s + k2 * c);
}

// ---------------------------------------------------------------------------
// Flash attention, swapped-QK^T 32x32x16 structure (m214 port).
// Block = 128 q-rows of one (b,h); 4 waves x QBLK=32; KVBLK=64.
// S^T = mfma(K, Q): lane owns one q-column -> in-register softmax.
// P: D-layout -> A-frag via cvt_pk + permlane32_swap (no LDS round-trip).
// K row-major in LDS; V^T staged via coalesced u16 gather + b128 writes.
// ---------------------------------------------------------------------------
#define PVAL(i) ((i) < 16 ? s0[(i) & 15] : s1[(i) & 15])

__global__ __launch_bounds__(256) void attn_mfma32(
    const unsigned short* __restrict__ Qb,
    const unsigned short* __restrict__ Kb,
    const unsigned short* __restrict__ Vb,
    unsigned short* __restrict__ Ob)
{
    __shared__ unsigned short Ks[64 * LSTR]; // [kv][d] row-major
    __shared__ unsigned short Vt[64 * LSTR]; // [d][kv] row-major (transposed V)

    const int tid = threadIdx.x;
    const int lane = tid & 63, wid = tid >> 6;
    const int q32 = lane & 31, hi = lane >> 5;
    const int bh = blockIdx.y, b = bh >> 4, h = bh & (NUM_HEADS - 1);
    const int q0 = blockIdx.x * 128 + wid * 32;

    // Q B-frags: qf[s] = Q[q0+q32][16s + 8hi .. +8]  (scale*log2e pre-folded)
    short8 qf[4];
    {
        const unsigned short* qsrc =
            Qb + (size_t)(b * T_SZ + q0 + q32) * D_MODEL + h * D_K + 8 * hi;
#pragma unroll
        for (int s = 0; s < 4; s++) qf[s] = *(const short8*)(qsrc + 16 * s);
    }

    f32x16 oacc0 = {}, oacc1 = {};
    float m = -INFINITY, l = 0.f;

    const int krow = tid >> 2, kcb = tid & 3;   // K staging
    const int vd = tid & 63, vblk = tid >> 6;   // V gather: kv0 = vblk*16
    const unsigned short* kbase = Kb + (size_t)b * T_SZ * D_MODEL + h * D_K;
    const unsigned short* vbase = Vb + (size_t)b * T_SZ * D_MODEL + h * D_K;

    for (int kt = 0; kt < T_SZ; kt += 64) {
        __syncthreads();
        { // stage K row-major
            const unsigned short* s = kbase + (size_t)(kt + krow) * D_MODEL + kcb * 16;
            short8 a0 = *(const short8*)s;
            short8 a1 = *(const short8*)(s + 8);
            *(short8*)&Ks[krow * LSTR + kcb * 16] = a0;
            *(short8*)&Ks[krow * LSTR + kcb * 16 + 8] = a1;
        }
        { // stage V transposed: coalesced u16 gather (lane = d), b128 writes
            const unsigned short* s = vbase + (size_t)(kt + vblk * 16) * D_MODEL + vd;
            unsigned short vals[16];
#pragma unroll
            for (int u = 0; u < 16; u++) vals[u] = s[(size_t)u * D_MODEL];
            short8 w0, w1;
#pragma unroll
            for (int u = 0; u < 8; u++) { w0[u] = (short)vals[u]; w1[u] = (short)vals[u + 8]; }
            *(short8*)&Vt[vd * LSTR + vblk * 16] = w0;
            *(short8*)&Vt[vd * LSTR + vblk * 16 + 8] = w1;
        }
        __syncthreads();

        // S^T = K * Q^T : D[kv][q], lane holds col q=q32, rows per C/D formula
        f32x16 s0 = {}, s1 = {};
#pragma unroll
        for (int s = 0; s < 4; s++) {
            short8 ak0 = *(const short8*)&Ks[q32 * LSTR + 16 * s + 8 * hi];
            short8 ak1 = *(const short8*)&Ks[(32 + q32) * LSTR + 16 * s + 8 * hi];
            s0 = __builtin_amdgcn_mfma_f32_32x32x16_bf16(ak0, qf[s], s0, 0, 0, 0);
            s1 = __builtin_amdgcn_mfma_f32_32x32x16_bf16(ak1, qf[s], s1, 0, 0, 0);
        }

        // ---- in-register online softmax (exp2 domain) ----
        float t8[8];
#pragma unroll
        for (int r = 0; r < 8; r++) t8[r] = fmaxf(fmaxf(s0[r], s0[r + 8]),
                                                  fmaxf(s1[r], s1[r + 8]));
        float pm = fmaxf(fmaxf(fmaxf(t8[0], t8[1]), fmaxf(t8[2], t8[3])),
                         fmaxf(fmaxf(t8[4], t8[5]), fmaxf(t8[6], t8[7])));
        pm = fmaxf(pm, __shfl_xor(pm, 32));

        if (!__all(pm <= m + 8.f)) { // defer-max (T13)
            float mn = fmaxf(m, pm);
            float sc = exp2f(m - mn);
            m = mn;
            l *= sc;
#pragma unroll
            for (int r = 0; r < 16; r++) { oacc0[r] *= sc; oacc1[r] *= sc; }
        }
        float ps = 0.f;
#pragma unroll
        for (int r = 0; r < 16; r++) { s0[r] = exp2f(s0[r] - m); }
#pragma unroll
        for (int r = 0; r < 16; r++) { s1[r] = exp2f(s1[r] - m); }
#pragma unroll
        for (int r = 0; r < 16; r++) ps += s0[r] + s1[r];
        ps += __shfl_xor(ps, 32);
        l += ps;

        // ---- P (D-layout) -> A-frags via cvt_pk + permlane32_swap; PV ----
#pragma unroll
        for (int t = 0; t < 4; t++) {
            const int b0 = 4 * ((2 * t + 0) & 3) + 16 * (t >> 1);
            const int b1 = 4 * ((2 * t + 1) & 3) + 16 * (t >> 1);
            int X0 = cvtpk(PVAL(b0), PVAL(b0 + 1));
            int X1 = cvtpk(PVAL(b0 + 2), PVAL(b0 + 3));
            int Y0 = cvtpk(PVAL(b1), PVAL(b1 + 1));
            int Y1 = cvtpk(PVAL(b1 + 2), PVAL(b1 + 3));
            asm("v_permlane32_swap_b32 %0, %1" : "+v"(X0), "+v"(Y0));
            asm("v_permlane32_swap_b32 %0, %1" : "+v"(X1), "+v"(Y1));
            union { int w[4]; short8 v; } af;
            af.w[0] = X0; af.w[1] = X1; af.w[2] = Y0; af.w[3] = Y1;
            short8 bv0 = *(const short8*)&Vt[q32 * LSTR + 16 * t + 8 * hi];
            short8 bv1 = *(const short8*)&Vt[(32 + q32) * LSTR + 16 * t + 8 * hi];
            oacc0 = __builtin_amdgcn_mfma_f32_32x32x16_bf16(af.v, bv0, oacc0, 0, 0, 0);
            oacc1 = __builtin_amdgcn_mfma_f32_32x32x16_bf16(af.v, bv1, oacc1, 0, 0, 0);
        }
    }

    // normalize + store (O: lane holds col d=q32 (+32), rows q=(r&3)+8(r>>2)+4hi)
    float invl = 1.f / l;
#pragma unroll
    for (int r = 0; r < 16; r++) {
        int qr = (r & 3) + 8 * (r >> 2) + 4 * hi;
        float iv = __shfl(invl, qr);
        size_t row = (size_t)(b * T_SZ + q0 + qr);
        Ob[row * D_MODEL + h * D_K + q32]      = f2bf(oacc0[r] * iv);
        Ob[row * D_MODEL + h * D_K + 32 + q32] = f2bf(oacc1[r] * iv);
    }
}

// ---------------------------------------------------------------------------
extern "C" void kernel_launch(void* const* d_in, const int* in_sizes, int n_in,
                              void* d_out, int out_size, void* d_ws, size_t ws_size,
                              hipStream_t stream)
{
    const float* x  = (const float*)d_in[0];
    const float* wq = (const float*)d_in[1];
    const float* wk = (const float*)d_in[2];
    const float* wv = (const float*)d_in[3];
    const float* wo = (const float*)d_in[4];
    float* out = (float*)d_out;

    const size_t NX = (size_t)M_ROWS * D_MODEL;  // 4M
    const size_t NW = (size_t)D_MODEL * D_MODEL; // 1M
    unsigned short* xb  = (unsigned short*)d_ws;
    unsigned short* wqb = xb + NX;
    unsigned short* wkb = wqb + NW;
    unsigned short* wvb = wkb + NW;
    unsigned short* wob = wvb + NW;
    unsigned short* Qb  = wob + NW;
    unsigned short* Kb  = Qb + NX;
    unsigned short* Vb  = Kb + NX;
    unsigned short* Ob  = Vb + NX;

    cvt_bf16<<<dim3((int)(NX / 8 / 256)), dim3(256), 0, stream>>>(x, xb, (int)(NX / 8));
    cvt_bf16<<<dim3((int)(NW / 8 / 256)), dim3(256), 0, stream>>>(wq, wqb, (int)(NW / 8));
    cvt_bf16<<<dim3((int)(NW / 8 / 256)), dim3(256), 0, stream>>>(wk, wkb, (int)(NW / 8));
    cvt_bf16<<<dim3((int)(NW / 8 / 256)), dim3(256), 0, stream>>>(wv, wvb, (int)(NW / 8));
    cvt_bf16<<<dim3((int)(NW / 8 / 256)), dim3(256), 0, stream>>>(wo, wob, (int)(NW / 8));

    gemm_qkv<<<dim3(D_MODEL / 128, M_ROWS / 128, 3), dim3(256), 0, stream>>>(
        xb, wqb, wkb, wvb, Qb, Kb, Vb);

    const int npairs = B_SZ * T_SZ * NUM_HEADS * 32;
    rope_bf16<<<dim3(npairs / 256), dim3(256), 0, stream>>>(Qb, Kb);

    attn_mfma32<<<dim3(T_SZ / 128, B_SZ * NUM_HEADS), dim3(256), 0, stream>>>(
        Qb, Kb, Vb, Ob);

    gemm_out<<<dim3(D_MODEL / 128, M_ROWS / 128), dim3(256), 0, stream>>>(Ob, wob, out);
}

// Round 4
// 223.007 us; speedup vs baseline: 4.7511x; 1.0851x over previous
//
#include <hip/hip_runtime.h>
#include <math.h>

typedef __attribute__((ext_vector_type(8))) short short8;
typedef __attribute__((ext_vector_type(4))) float f32x4;
typedef __attribute__((ext_vector_type(16))) float f32x16;

#define D_MODEL 1024
#define NUM_HEADS 16
#define D_K 64
#define B_SZ 2
#define T_SZ 2048
#define M_ROWS (B_SZ * T_SZ) // 4096
#define LSTR 72              // LDS row stride (bf16 elems): 144B
#define LOG2E 1.4426950408889634f
#define KVSPLIT 1024

__device__ __forceinline__ unsigned short f2bf(float f) {
    union { float f; unsigned int u; } v; v.f = f;
    unsigned int r = v.u + 0x7FFF + ((v.u >> 16) & 1); // RNE
    return (unsigned short)(r >> 16);
}
__device__ __forceinline__ void gload_lds16(const void* g, void* l) {
    __builtin_amdgcn_global_load_lds(
        (const __attribute__((address_space(1))) unsigned int*)g,
        (__attribute__((address_space(3))) unsigned int*)l, 16, 0, 0);
}
__device__ __forceinline__ int cvtpk(float lo, float hi) {
    int r;
    asm("v_cvt_pk_bf16_f32 %0, %1, %2" : "=v"(r) : "v"(lo), "v"(hi));
    return r;
}

// ---------------------------------------------------------------------------
// One-launch fp32 -> bf16 conversion for x + 4 weights (dst contiguous in ws)
// ---------------------------------------------------------------------------
__global__ __launch_bounds__(256) void cvt_all(
    const float* __restrict__ x,  const float* __restrict__ w0,
    const float* __restrict__ w1, const float* __restrict__ w2,
    const float* __restrict__ w3, unsigned short* __restrict__ dst)
{
    const size_t NX8 = (size_t)M_ROWS * D_MODEL / 8;           // 524288
    const size_t NW8 = (size_t)D_MODEL * D_MODEL / 8;          // 131072
    size_t i = (size_t)blockIdx.x * 256 + threadIdx.x;
    const float* src; size_t off;
    if (i < NX8) { src = x; off = i; }
    else {
        size_t j = i - NX8;
        int ws = (int)(j >> 17);
        off = j & (NW8 - 1);
        src = (ws == 0) ? w0 : (ws == 1) ? w1 : (ws == 2) ? w2 : w3;
    }
    const float4* p = (const float4*)src + 2 * off;
    float4 a = p[0], b = p[1];
    short8 o;
    o[0] = f2bf(a.x); o[1] = f2bf(a.y); o[2] = f2bf(a.z); o[3] = f2bf(a.w);
    o[4] = f2bf(b.x); o[5] = f2bf(b.y); o[6] = f2bf(b.z); o[7] = f2bf(b.w);
    *((short8*)dst + i) = o;
}

// ---------------------------------------------------------------------------
// RoPE cos/sin table: [t][i] float2, t<2048, i<32. Accurate invf (double pow).
// ---------------------------------------------------------------------------
__global__ __launch_bounds__(256) void rope_table(float2* __restrict__ tab)
{
    int idx = blockIdx.x * 256 + threadIdx.x; // < 65536
    int t = idx >> 5, i = idx & 31;
    const float invf = (float)pow(10000.0, -(double)i / 32.0);
    float s, c;
    sincosf((float)t * invf, &s, &c);
    tab[idx] = make_float2(c, s);
}

// ---------------------------------------------------------------------------
// bf16 MFMA GEMM (NT) with fused RoPE epilogue. m97 structure: 128x128, BK=32,
// 4 waves, global_load_lds(16B). z: 0=Q (rotate+0.125*log2e), 1=K (rotate),
// 2=V (plain). Pair (d,d+32) = (nf,nf+2), same lane.
// ---------------------------------------------------------------------------
__global__ __launch_bounds__(256) void gemm_qkv(
    const unsigned short* __restrict__ Xb,
    const unsigned short* __restrict__ Wq,
    const unsigned short* __restrict__ Wk,
    const unsigned short* __restrict__ Wv,
    unsigned short* __restrict__ Qb,
    unsigned short* __restrict__ Kb,
    unsigned short* __restrict__ Vb,
    const float2* __restrict__ tab)
{
    const int z = blockIdx.z;
    const unsigned short* W = (z == 0) ? Wq : (z == 1) ? Wk : Wv;
    unsigned short* Y = (z == 0) ? Qb : (z == 1) ? Kb : Vb;

    __shared__ unsigned short Als[128 * 32];
    __shared__ unsigned short Bls[128 * 32];

    const int tid = threadIdx.x;
    const int lane = tid & 63, wid = tid >> 6;
    const int g = lane >> 4, c16 = lane & 15;
    const int wr = wid >> 1, wc = wid & 1;
    const int m0 = blockIdx.y * 128, n0 = blockIdx.x * 128;

    const int sr = tid >> 2, sc = (tid & 3) * 8;
    const unsigned short* xg = Xb + (size_t)(m0 + sr) * D_MODEL + sc;
    const unsigned short* wg = W + (size_t)(n0 + sr) * D_MODEL + sc;
    unsigned short* adst = Als + wid * 512;
    unsigned short* bdst = Bls + wid * 512;

    f32x4 acc[4][4] = {};

    for (int k0 = 0; k0 < D_MODEL; k0 += 32) {
        __syncthreads();
        gload_lds16(xg + k0, adst);
        gload_lds16(xg + k0 + (size_t)64 * D_MODEL, adst + 2048);
        gload_lds16(wg + k0, bdst);
        gload_lds16(wg + k0 + (size_t)64 * D_MODEL, bdst + 2048);
        __syncthreads();
        short8 af[4], bf[4];
#pragma unroll
        for (int mf = 0; mf < 4; mf++)
            af[mf] = *(const short8*)&Als[(wr * 64 + mf * 16 + c16) * 32 + g * 8];
#pragma unroll
        for (int nf = 0; nf < 4; nf++)
            bf[nf] = *(const short8*)&Bls[(wc * 64 + nf * 16 + c16) * 32 + g * 8];
#pragma unroll
        for (int mf = 0; mf < 4; mf++)
#pragma unroll
            for (int nf = 0; nf < 4; nf++)
                acc[mf][nf] = __builtin_amdgcn_mfma_f32_16x16x32_bf16(
                    af[mf], bf[nf], acc[mf][nf], 0, 0, 0);
    }

    if (z < 2) { // fused RoPE on Q/K (Q also scaled by 0.125*log2e)
        const float qs = (z == 0) ? 0.125f * LOG2E : 1.0f;
#pragma unroll
        for (int mf = 0; mf < 4; mf++)
#pragma unroll
            for (int j = 0; j < 4; j++) {
                int row = m0 + wr * 64 + mf * 16 + g * 4 + j;
                int t = row & (T_SZ - 1);
#pragma unroll
                for (int nf = 0; nf < 2; nf++) {
                    float2 cs = tab[t * 32 + nf * 16 + c16];
                    float a = acc[mf][nf][j], b2 = acc[mf][nf + 2][j];
                    acc[mf][nf][j]     = (a * cs.x - b2 * cs.y) * qs;
                    acc[mf][nf + 2][j] = (a * cs.y + b2 * cs.x) * qs;
                }
            }
    }

#pragma unroll
    for (int mf = 0; mf < 4; mf++)
#pragma unroll
        for (int nf = 0; nf < 4; nf++)
#pragma unroll
            for (int j = 0; j < 4; j++) {
                int row = m0 + wr * 64 + mf * 16 + g * 4 + j;
                int col = n0 + wc * 64 + nf * 16 + c16;
                Y[(size_t)row * D_MODEL + col] = f2bf(acc[mf][nf][j]);
            }
}

// ---------------------------------------------------------------------------
// Output GEMM, 128x64 tile (2 blocks/CU), bf16 in -> fp32 out.
// 4 waves 2x2; wave tile 64x32; BK=32.
// ---------------------------------------------------------------------------
__global__ __launch_bounds__(256) void gemm_out(
    const unsigned short* __restrict__ Xb,
    const unsigned short* __restrict__ W,
    float* __restrict__ Y)
{
    __shared__ unsigned short Als[128 * 32];
    __shared__ unsigned short Bls[64 * 32];

    const int tid = threadIdx.x;
    const int lane = tid & 63, wid = tid >> 6;
    const int g = lane >> 4, c16 = lane & 15;
    const int wr = wid >> 1, wc = wid & 1;
    const int m0 = blockIdx.y * 128, n0 = blockIdx.x * 64;

    const int sr = tid >> 2, sc = (tid & 3) * 8;
    const unsigned short* xg = Xb + (size_t)(m0 + sr) * D_MODEL + sc;
    const unsigned short* wg = W + (size_t)(n0 + sr) * D_MODEL + sc;
    unsigned short* adst = Als + wid * 512;
    unsigned short* bdst = Bls + wid * 512;

    f32x4 acc[4][2] = {};

    for (int k0 = 0; k0 < D_MODEL; k0 += 32) {
        __syncthreads();
        gload_lds16(xg + k0, adst);
        gload_lds16(xg + k0 + (size_t)64 * D_MODEL, adst + 2048);
        gload_lds16(wg + k0, bdst);
        __syncthreads();
        short8 af[4], bf[2];
#pragma unroll
        for (int mf = 0; mf < 4; mf++)
            af[mf] = *(const short8*)&Als[(wr * 64 + mf * 16 + c16) * 32 + g * 8];
#pragma unroll
        for (int nf = 0; nf < 2; nf++)
            bf[nf] = *(const short8*)&Bls[(wc * 32 + nf * 16 + c16) * 32 + g * 8];
#pragma unroll
        for (int mf = 0; mf < 4; mf++)
#pragma unroll
            for (int nf = 0; nf < 2; nf++)
                acc[mf][nf] = __builtin_amdgcn_mfma_f32_16x16x32_bf16(
                    af[mf], bf[nf], acc[mf][nf], 0, 0, 0);
    }

#pragma unroll
    for (int mf = 0; mf < 4; mf++)
#pragma unroll
        for (int nf = 0; nf < 2; nf++)
#pragma unroll
            for (int j = 0; j < 4; j++) {
                int row = m0 + wr * 64 + mf * 16 + g * 4 + j;
                int col = n0 + wc * 32 + nf * 16 + c16;
                Y[(size_t)row * D_MODEL + col] = acc[mf][nf][j];
            }
}

// ---------------------------------------------------------------------------
// Flash attention, swapped-QK^T 32x32x16, in-block KV-split.
// 8 waves: kz=wid>>2 takes kv half, wq=wid&3 takes 32 q-rows of the block's
// 128. Per-half K/V^T staged in LDS; T14 reg-prefetch across raw barriers;
// in-LDS combine of the two halves at the end.
// ---------------------------------------------------------------------------
#define PVAL(i) ((i) < 16 ? s0[(i) & 15] : s1[(i) & 15])

__global__ __launch_bounds__(512, 4) void attn_mfma32(
    const unsigned short* __restrict__ Qb,
    const unsigned short* __restrict__ Kb,
    const unsigned short* __restrict__ Vb,
    unsigned short* __restrict__ Ob)
{
    __shared__ __align__(16) char smem[36864]; // 2 x (K 9216B + Vt 9216B); reused for combine

    const int tid = threadIdx.x;
    const int lane = tid & 63, wid = tid >> 6;
    const int kz = wid >> 2, wq = wid & 3;
    const int q32 = lane & 31, hi = lane >> 5;
    const int bh = blockIdx.y, b = bh >> 4, h = bh & (NUM_HEADS - 1);
    const int q0 = blockIdx.x * 128 + wq * 32;

    unsigned short* Ks = (unsigned short*)(smem + kz * 18432);
    unsigned short* Vt = Ks + 64 * LSTR;

    // Q B-frags (0.125*log2e pre-folded in projection epilogue)
    short8 qf[4];
    {
        const unsigned short* qsrc =
            Qb + (size_t)(b * T_SZ + q0 + q32) * D_MODEL + h * D_K + 8 * hi;
#pragma unroll
        for (int s = 0; s < 4; s++) qf[s] = *(const short8*)(qsrc + 16 * s);
    }

    f32x16 oacc0 = {}, oacc1 = {};
    float m = -INFINITY, l = 0.f;

    const int t256 = tid & 255;
    const int krow = t256 >> 2, kcb = t256 & 3;   // K staging
    const int vd = t256 & 63, vblk = t256 >> 6;   // V gather: kv0 = vblk*16
    const unsigned short* kbase =
        Kb + (size_t)(b * T_SZ + kz * KVSPLIT) * D_MODEL + h * D_K;
    const unsigned short* vbase =
        Vb + (size_t)(b * T_SZ + kz * KVSPLIT) * D_MODEL + h * D_K;

    short8 pk0, pk1;
    unsigned short pv[16];
#define LOAD_KV(KT) do { \
    const unsigned short* _s = kbase + (size_t)((KT) + krow) * D_MODEL + kcb * 16; \
    pk0 = *(const short8*)_s; pk1 = *(const short8*)(_s + 8); \
    const unsigned short* _v = vbase + (size_t)((KT) + vblk * 16) * D_MODEL + vd; \
    _Pragma("unroll") for (int u = 0; u < 16; u++) pv[u] = _v[(size_t)u * D_MODEL]; \
  } while (0)

    LOAD_KV(0);

    for (int kt = 0; kt < KVSPLIT; kt += 64) {
        // barrier A: everyone done reading LDS tile kt-64
        __builtin_amdgcn_sched_barrier(0);
        __builtin_amdgcn_s_barrier();
        __builtin_amdgcn_sched_barrier(0);
        // write prefetched tile (vmcnt waits inserted here by compiler)
        *(short8*)&Ks[krow * LSTR + kcb * 16] = pk0;
        *(short8*)&Ks[krow * LSTR + kcb * 16 + 8] = pk1;
        {
            short8 w0, w1;
#pragma unroll
            for (int u = 0; u < 8; u++) { w0[u] = (short)pv[u]; w1[u] = (short)pv[u + 8]; }
            *(short8*)&Vt[vd * LSTR + vblk * 16] = w0;
            *(short8*)&Vt[vd * LSTR + vblk * 16 + 8] = w1;
        }
        // issue next tile's loads — stay in flight through compute
        if (kt + 64 < KVSPLIT) LOAD_KV(kt + 64);
        // barrier B: LDS writes drained (lgkm only; vm loads keep flying)
        asm volatile("s_waitcnt lgkmcnt(0)" ::: "memory");
        __builtin_amdgcn_s_barrier();
        __builtin_amdgcn_sched_barrier(0);

        // S^T = K * Q^T : lane holds q-col q32, regs = kv rows
        f32x16 s0 = {}, s1 = {};
#pragma unroll
        for (int s = 0; s < 4; s++) {
            short8 ak0 = *(const short8*)&Ks[q32 * LSTR + 16 * s + 8 * hi];
            short8 ak1 = *(const short8*)&Ks[(32 + q32) * LSTR + 16 * s + 8 * hi];
            s0 = __builtin_amdgcn_mfma_f32_32x32x16_bf16(ak0, qf[s], s0, 0, 0, 0);
            s1 = __builtin_amdgcn_mfma_f32_32x32x16_bf16(ak1, qf[s], s1, 0, 0, 0);
        }

        // in-register online softmax (exp2 domain)
        float t8[8];
#pragma unroll
        for (int r = 0; r < 8; r++) t8[r] = fmaxf(fmaxf(s0[r], s0[r + 8]),
                                                  fmaxf(s1[r], s1[r + 8]));
        float pm = fmaxf(fmaxf(fmaxf(t8[0], t8[1]), fmaxf(t8[2], t8[3])),
                         fmaxf(fmaxf(t8[4], t8[5]), fmaxf(t8[6], t8[7])));
        pm = fmaxf(pm, __shfl_xor(pm, 32));

        if (!__all(pm <= m + 8.f)) { // defer-max (T13)
            float mn = fmaxf(m, pm);
            float sc = exp2f(m - mn);
            m = mn;
            l *= sc;
#pragma unroll
            for (int r = 0; r < 16; r++) { oacc0[r] *= sc; oacc1[r] *= sc; }
        }
        float ps = 0.f;
#pragma unroll
        for (int r = 0; r < 16; r++) s0[r] = exp2f(s0[r] - m);
#pragma unroll
        for (int r = 0; r < 16; r++) s1[r] = exp2f(s1[r] - m);
#pragma unroll
        for (int r = 0; r < 16; r++) ps += s0[r] + s1[r];
        ps += __shfl_xor(ps, 32);
        l += ps;

        // P (D-layout) -> A-frags via cvt_pk + permlane32_swap; O += P V
#pragma unroll
        for (int t = 0; t < 4; t++) {
            const int b0 = 4 * ((2 * t + 0) & 3) + 16 * (t >> 1);
            const int b1 = 4 * ((2 * t + 1) & 3) + 16 * (t >> 1);
            int X0 = cvtpk(PVAL(b0), PVAL(b0 + 1));
            int X1 = cvtpk(PVAL(b0 + 2), PVAL(b0 + 3));
            int Y0 = cvtpk(PVAL(b1), PVAL(b1 + 1));
            int Y1 = cvtpk(PVAL(b1 + 2), PVAL(b1 + 3));
            asm("v_permlane32_swap_b32 %0, %1" : "+v"(X0), "+v"(Y0));
            asm("v_permlane32_swap_b32 %0, %1" : "+v"(X1), "+v"(Y1));
            union { int w[4]; short8 v; } af;
            af.w[0] = X0; af.w[1] = X1; af.w[2] = Y0; af.w[3] = Y1;
            short8 bv0 = *(const short8*)&Vt[q32 * LSTR + 16 * t + 8 * hi];
            short8 bv1 = *(const short8*)&Vt[(32 + q32) * LSTR + 16 * t + 8 * hi];
            oacc0 = __builtin_amdgcn_mfma_f32_32x32x16_bf16(af.v, bv0, oacc0, 0, 0, 0);
            oacc1 = __builtin_amdgcn_mfma_f32_32x32x16_bf16(af.v, bv1, oacc1, 0, 0, 0);
        }
    }

    // ---- combine the two kv-halves in LDS ----
    __syncthreads();
    float* cmbO = (float*)smem;              // [wq][q (32)][d (64)]
    float* mlb  = (float*)(smem + 32768);    // [wq][{m,l}][q32]
    if (kz == 1) {
        if (hi == 0) { mlb[wq * 64 + q32] = m; mlb[wq * 64 + 32 + q32] = l; }
#pragma unroll
        for (int r = 0; r < 16; r++) {
            int qr = (r & 3) + 8 * (r >> 2) + 4 * hi;
            cmbO[wq * 2048 + qr * 64 + q32]      = oacc0[r];
            cmbO[wq * 2048 + qr * 64 + 32 + q32] = oacc1[r];
        }
    }
    __syncthreads();
    if (kz == 0) {
        float mB = mlb[wq * 64 + q32], lB = mlb[wq * 64 + 32 + q32];
        float M = fmaxf(m, mB);
        float sA = exp2f(m - M), sB = exp2f(mB - M);
        float linv = 1.f / (l * sA + lB * sB);
        float fA = sA * linv, fB = sB * linv;
#pragma unroll
        for (int r = 0; r < 16; r++) {
            int qr = (r & 3) + 8 * (r >> 2) + 4 * hi;
            float gA = __shfl(fA, qr), gB = __shfl(fB, qr);
            float o0 = oacc0[r] * gA + cmbO[wq * 2048 + qr * 64 + q32] * gB;
            float o1 = oacc1[r] * gA + cmbO[wq * 2048 + qr * 64 + 32 + q32] * gB;
            size_t row = (size_t)(b * T_SZ + q0 + qr);
            Ob[row * D_MODEL + h * D_K + q32]      = f2bf(o0);
            Ob[row * D_MODEL + h * D_K + 32 + q32] = f2bf(o1);
        }
    }
}

// ---------------------------------------------------------------------------
extern "C" void kernel_launch(void* const* d_in, const int* in_sizes, int n_in,
                              void* d_out, int out_size, void* d_ws, size_t ws_size,
                              hipStream_t stream)
{
    const float* x  = (const float*)d_in[0];
    const float* wq = (const float*)d_in[1];
    const float* wk = (const float*)d_in[2];
    const float* wv = (const float*)d_in[3];
    const float* wo = (const float*)d_in[4];
    float* out = (float*)d_out;

    const size_t NX = (size_t)M_ROWS * D_MODEL;  // 4M
    const size_t NW = (size_t)D_MODEL * D_MODEL; // 1M
    unsigned short* xb  = (unsigned short*)d_ws;
    unsigned short* wqb = xb + NX;
    unsigned short* wkb = wqb + NW;
    unsigned short* wvb = wkb + NW;
    unsigned short* wob = wvb + NW;
    unsigned short* Qb  = wob + NW;
    unsigned short* Kb  = Qb + NX;
    unsigned short* Vb  = Kb + NX;
    unsigned short* Ob  = Vb + NX;
    float2* tab = (float2*)(Ob + NX); // 2048*32 float2 = 512KB

    const int ncvt8 = (int)((NX + 4 * NW) / 8); // 1048576
    cvt_all<<<dim3(ncvt8 / 256), dim3(256), 0, stream>>>(x, wq, wk, wv, wo, xb);
    rope_table<<<dim3(T_SZ * 32 / 256), dim3(256), 0, stream>>>(tab);

    gemm_qkv<<<dim3(D_MODEL / 128, M_ROWS / 128, 3), dim3(256), 0, stream>>>(
        xb, wqb, wkb, wvb, Qb, Kb, Vb, tab);

    attn_mfma32<<<dim3(T_SZ / 128, B_SZ * NUM_HEADS), dim3(512), 0, stream>>>(
        Qb, Kb, Vb, Ob);

    gemm_out<<<dim3(D_MODEL / 64, M_ROWS / 128), dim3(256), 0, stream>>>(Ob, wob, out);
}